// Round 2
// baseline (14455.673 us; speedup 1.0000x reference)
//
#include <hip/hip_runtime.h>
#include <hip/hip_bf16.h>

// Problem constants
#define B_    512
#define HIST_ 8
#define PRED_ 24
#define CITY_ 184
#define FEAT_ 13
#define HID_  32
#define BC_   (B_*CITY_)   // 94208 = 1472 * 64

// ws (float) layout:
//   [0      .. 4095 ]  Wh2[row*32+k]  row=0..127 : W_hh + a0 (x) W_out   (used t>=1)
//   [4096   .. 6143 ]  Wf [row*16+f]  f=0..12    : W_x[:,1:14]           (all t)
//   [6144   .. 6271 ]  bg2[row]                  : b_g + a0*b_out        (t>=1)
//   [6272   .. 6399 ]  a0 [row]                  : W_x[:,0]              (t==0)
//   [6400   .. 6527 ]  bg0[row]                  : b_g                   (t==0)
//   [6528   .. 6559 ]  wout[k]
//   [6560]             bout
//   [7168]             dtype flag: 0.0f = inputs are bf16, 1.0f = inputs are fp32
#define FLAG_OFF 7168

__device__ __forceinline__ float rcp_(float x) { return __builtin_amdgcn_rcpf(x); }
__device__ __forceinline__ float sigf(float x) { return rcp_(1.0f + __expf(-x)); }
__device__ __forceinline__ float tanhf_(float x) {
    float e = __expf(2.0f * x);
    return 1.0f - 2.0f * rcp_(e + 1.0f);   // saturates correctly at +/-inf
}

template<bool F32>
__device__ __forceinline__ float ldin(const void* p, long i) {
    if constexpr (F32) return ((const float*)p)[i];
    else               return __bfloat162float(((const __hip_bfloat16*)p)[i]);
}
template<bool F32>
__device__ __forceinline__ void stout(void* p, long i, float v) {
    if constexpr (F32) ((float*)p)[i] = v;
    else               ((__hip_bfloat16*)p)[i] = __float2bfloat16(v);
}

// ---- dtype detector: reads first 4096 elements of `feature` as bf16. ----
// True bf16 N(0,1) data: no |x|>1e8 / NaN. fp32 data misread as bf16: the low
// half of every float decodes to garbage (~26% insane). Threshold 8.
__global__ void detect_dtype(const unsigned short* __restrict__ feat_raw,
                             float* __restrict__ ws) {
    __shared__ int cnt;
    int tid = threadIdx.x;
    if (tid == 0) cnt = 0;
    __syncthreads();
    int insane = 0;
    for (int i = tid; i < 4096; i += 256) {
        float v = __uint_as_float(((unsigned int)feat_raw[i]) << 16);
        if (!(fabsf(v) < 1e8f)) insane++;   // catches NaN too
    }
    if (insane) atomicAdd(&cnt, insane);
    __syncthreads();
    if (tid == 0) ws[FLAG_OFF] = (cnt > 8) ? 1.0f : 0.0f;
}

template<bool F32>
__global__ void lstm_prep(const void* __restrict__ W_in,   // (32,14)
                          const void* __restrict__ b_in,   // (32)
                          const void* __restrict__ W_out,  // (1,32)
                          const void* __restrict__ b_out,  // (1)
                          const void* __restrict__ W_ih,   // (128,32)
                          const void* __restrict__ W_hh,   // (128,32)
                          const void* __restrict__ b_ih,   // (128)
                          const void* __restrict__ b_hh,   // (128)
                          float* __restrict__ ws)
{
    if (ws[FLAG_OFF] != (F32 ? 1.0f : 0.0f)) return;   // wrong-dtype instance
    int j = threadIdx.x;           // gate row 0..127
    if (j >= 128) return;

    float wx[14];
    #pragma unroll
    for (int c = 0; c < 14; ++c) wx[c] = 0.0f;
    float bg = ldin<F32>(b_ih, j) + ldin<F32>(b_hh, j);
    #pragma unroll
    for (int m = 0; m < 32; ++m) {
        float wihm = ldin<F32>(W_ih, j*32 + m);
        #pragma unroll
        for (int c = 0; c < 14; ++c) wx[c] = fmaf(wihm, ldin<F32>(W_in, m*14 + c), wx[c]);
        bg = fmaf(wihm, ldin<F32>(b_in, m), bg);
    }
    float a0 = wx[0];
    #pragma unroll
    for (int k = 0; k < 32; ++k)
        ws[j*32 + k] = ldin<F32>(W_hh, j*32 + k) + a0 * ldin<F32>(W_out, k);
    #pragma unroll
    for (int f = 0; f < 13; ++f) ws[4096 + j*16 + f] = wx[1 + f];
    float bo = ldin<F32>(b_out, 0);
    ws[6144 + j] = bg + a0 * bo;
    ws[6272 + j] = a0;
    ws[6400 + j] = bg;
    if (j < 32) ws[6528 + j] = ldin<F32>(W_out, j);
    if (j == 0) ws[6560] = bo;
}

template<bool F32>
__global__ __launch_bounds__(256, 4) void lstm_main(
    const void* __restrict__ pm25,   // (512, 8, 184, 1)
    const void* __restrict__ feat,   // (512, 32, 184, 13)
    const float* __restrict__ ws,
    void* __restrict__ out)          // (512, 24, 184, 1)
{
    __shared__ float hbuf[2][64][33];          // +1 pad -> 2-way bank alias (free)
    if (ws[FLAG_OFF] != (F32 ? 1.0f : 0.0f)) return;   // wrong-dtype instance

    const int lane  = threadIdx.x & 63;
    const int sub   = threadIdx.x >> 6;        // wave-uniform
    const int s     = blockIdx.x * 64 + lane;  // sequence id, grid exact
    const int b     = s / CITY_;
    const int city  = s - b * CITY_;
    const int ubase = sub * 8;

    const float* __restrict__ Wh2  = ws;
    const float* __restrict__ Wf   = ws + 4096;
    const float* __restrict__ bg2  = ws + 6144;
    const float* __restrict__ a0v  = ws + 6272;
    const float* __restrict__ bg0  = ws + 6400;
    const float* __restrict__ wout = ws + 6528;

    float c[8];
    const float x0 = ldin<F32>(pm25, (long)(b*HIST_ + (HIST_-1))*CITY_ + city);

    long fbase = ((long)(b*(HIST_+PRED_) + HIST_) * CITY_ + city) * FEAT_;

    float ft[FEAT_];
    #pragma unroll
    for (int f = 0; f < FEAT_; ++f) ft[f] = ldin<F32>(feat, fbase + f);

    // ---- t = 0 : h0 = c0 = 0, x comes from pm25 ----
    #pragma unroll
    for (int uu = 0; uu < 8; ++uu) {
        const int u = ubase + uu;
        float ai = fmaf(a0v[u   ], x0, bg0[u   ]);
        float ag = fmaf(a0v[u+64], x0, bg0[u+64]);
        float ao = fmaf(a0v[u+96], x0, bg0[u+96]);
        #pragma unroll
        for (int f = 0; f < FEAT_; ++f) {
            const float fv = ft[f];
            ai = fmaf(Wf[(u   )*16 + f], fv, ai);
            ag = fmaf(Wf[(u+64)*16 + f], fv, ag);
            ao = fmaf(Wf[(u+96)*16 + f], fv, ao);
        }
        const float cc = sigf(ai) * tanhf_(ag);   // f-gate row skipped: c0 == 0
        c[uu] = cc;
        hbuf[0][lane][u] = sigf(ao) * tanhf_(cc); // h1
    }

    // ---- t = 1 .. 23 ----
    #pragma unroll 1
    for (int t = 1; t < PRED_; ++t) {
        fbase += CITY_ * FEAT_;
        #pragma unroll
        for (int f = 0; f < FEAT_; ++f) ft[f] = ldin<F32>(feat, fbase + f);

        __syncthreads();
        const int Rb = (t + 1) & 1;   // holds h_t
        const int Wb = t & 1;         // receives h_{t+1}

        float h[32];
        #pragma unroll
        for (int k = 0; k < 32; ++k) h[k] = hbuf[Rb][lane][k];

        if (sub == 0) {               // y_{t-1} = wout . h_t + bout
            float y = ws[6560];
            #pragma unroll
            for (int k = 0; k < 32; ++k) y = fmaf(wout[k], h[k], y);
            stout<F32>(out, (long)(b*PRED_ + (t-1))*CITY_ + city, y);
        }

        #pragma unroll
        for (int uu = 0; uu < 8; ++uu) {
            const int u = ubase + uu;
            float ai = bg2[u], af = bg2[u+32], ag = bg2[u+64], ao = bg2[u+96];
            #pragma unroll
            for (int k = 0; k < 32; ++k) {
                const float hk = h[k];
                ai = fmaf(Wh2[(u   )*32 + k], hk, ai);
                af = fmaf(Wh2[(u+32)*32 + k], hk, af);
                ag = fmaf(Wh2[(u+64)*32 + k], hk, ag);
                ao = fmaf(Wh2[(u+96)*32 + k], hk, ao);
            }
            #pragma unroll
            for (int f = 0; f < FEAT_; ++f) {
                const float fv = ft[f];
                ai = fmaf(Wf[(u   )*16 + f], fv, ai);
                af = fmaf(Wf[(u+32)*16 + f], fv, af);
                ag = fmaf(Wf[(u+64)*16 + f], fv, ag);
                ao = fmaf(Wf[(u+96)*16 + f], fv, ao);
            }
            const float cc = fmaf(sigf(af), c[uu], sigf(ai) * tanhf_(ag));
            c[uu] = cc;
            hbuf[Wb][lane][u] = sigf(ao) * tanhf_(cc);
        }
    }

    // ---- epilogue: y_23 from h_24 (in hbuf[1]) ----
    __syncthreads();
    if (sub == 0) {
        float y = ws[6560];
        #pragma unroll
        for (int k = 0; k < 32; ++k) y = fmaf(wout[k], hbuf[1][lane][k], y);
        stout<F32>(out, (long)(b*PRED_ + (PRED_-1))*CITY_ + city, y);
    }
}

extern "C" void kernel_launch(void* const* d_in, const int* in_sizes, int n_in,
                              void* d_out, int out_size, void* d_ws, size_t ws_size,
                              hipStream_t stream) {
    const void* pm25  = d_in[0];
    const void* feat  = d_in[1];
    const void* W_in  = d_in[2];
    const void* b_in  = d_in[3];
    const void* W_out = d_in[4];
    const void* b_out = d_in[5];
    const void* W_ih  = d_in[6];
    const void* W_hh  = d_in[7];
    const void* b_ih  = d_in[8];
    const void* b_hh  = d_in[9];
    float* ws = (float*)d_ws;

    detect_dtype<<<dim3(1), dim3(256), 0, stream>>>((const unsigned short*)feat, ws);

    lstm_prep<false><<<dim3(1), dim3(128), 0, stream>>>(
        W_in, b_in, W_out, b_out, W_ih, W_hh, b_ih, b_hh, ws);
    lstm_prep<true><<<dim3(1), dim3(128), 0, stream>>>(
        W_in, b_in, W_out, b_out, W_ih, W_hh, b_ih, b_hh, ws);

    lstm_main<false><<<dim3(BC_/64), dim3(256), 0, stream>>>(pm25, feat, ws, d_out);
    lstm_main<true ><<<dim3(BC_/64), dim3(256), 0, stream>>>(pm25, feat, ws, d_out);
}

// Round 3
// 679.865 us; speedup vs baseline: 21.2626x; 21.2626x over previous
//
#include <hip/hip_runtime.h>
#include <hip/hip_bf16.h>

// Problem constants
#define B_    512
#define HIST_ 8
#define PRED_ 24
#define CITY_ 184
#define FEAT_ 13
#define HID_  32
#define BC_   (B_*CITY_)   // 94208 = 5888 * 16
#define FLAG_OFF 7168

// ws (float) layout (written by lstm_prep):
//   [0..4095]      Wh2[row*32+k] : W_hh + a0 (x) W_out   (t>=1 path)
//   [4096..6143]   Wf [row*16+f] : W_x[:,1:14], cols 13..15 zeroed
//   [6144..6271]   bg2[row]      : b_g + a0*b_out        (t>=1)
//   [6272..6399]   a0 [row]      : W_x[:,0]              (t==0)
//   [6400..6527]   bg0[row]      : b_g                   (t==0)
//   [6528..6559]   wout[k]
//   [6560]         bout
//   [7168]         dtype flag: 0.0f = bf16 inputs, 1.0f = fp32 inputs

struct TrueT  { static constexpr bool value = true;  };
struct FalseT { static constexpr bool value = false; };

__device__ __forceinline__ float rcp_(float x) { return __builtin_amdgcn_rcpf(x); }
__device__ __forceinline__ float sigf(float x) { return rcp_(1.0f + __expf(-x)); }
__device__ __forceinline__ float tanhf_(float x) {
    float e = __expf(2.0f * x);
    return 1.0f - 2.0f * rcp_(e + 1.0f);   // saturates correctly
}

template<bool F32>
__device__ __forceinline__ float ldin(const void* p, long i) {
    if constexpr (F32) return ((const float*)p)[i];
    else               return __bfloat162float(((const __hip_bfloat16*)p)[i]);
}
template<bool F32>
__device__ __forceinline__ void stout(void* p, long i, float v) {
    if constexpr (F32) ((float*)p)[i] = v;
    else               ((__hip_bfloat16*)p)[i] = __float2bfloat16(v);
}

// ---- dtype detector (validated in R2) ----
__global__ void detect_dtype(const unsigned short* __restrict__ feat_raw,
                             float* __restrict__ ws) {
    __shared__ int cnt;
    int tid = threadIdx.x;
    if (tid == 0) cnt = 0;
    __syncthreads();
    int insane = 0;
    for (int i = tid; i < 4096; i += 256) {
        float v = __uint_as_float(((unsigned int)feat_raw[i]) << 16);
        if (!(fabsf(v) < 1e8f)) insane++;
    }
    if (insane) atomicAdd(&cnt, insane);
    __syncthreads();
    if (tid == 0) ws[FLAG_OFF] = (cnt > 8) ? 1.0f : 0.0f;
}

template<bool F32>
__global__ void lstm_prep(const void* __restrict__ W_in,   // (32,14)
                          const void* __restrict__ b_in,   // (32)
                          const void* __restrict__ W_out,  // (1,32)
                          const void* __restrict__ b_out,  // (1)
                          const void* __restrict__ W_ih,   // (128,32)
                          const void* __restrict__ W_hh,   // (128,32)
                          const void* __restrict__ b_ih,   // (128)
                          const void* __restrict__ b_hh,   // (128)
                          float* __restrict__ ws)
{
    if (ws[FLAG_OFF] != (F32 ? 1.0f : 0.0f)) return;
    int j = threadIdx.x;           // gate row 0..127
    if (j >= 128) return;

    float wx[14];
    #pragma unroll
    for (int c = 0; c < 14; ++c) wx[c] = 0.0f;
    float bg = ldin<F32>(b_ih, j) + ldin<F32>(b_hh, j);
    #pragma unroll
    for (int m = 0; m < 32; ++m) {
        float wihm = ldin<F32>(W_ih, j*32 + m);
        #pragma unroll
        for (int c = 0; c < 14; ++c) wx[c] = fmaf(wihm, ldin<F32>(W_in, m*14 + c), wx[c]);
        bg = fmaf(wihm, ldin<F32>(b_in, m), bg);
    }
    float a0 = wx[0];
    #pragma unroll
    for (int k = 0; k < 32; ++k)
        ws[j*32 + k] = ldin<F32>(W_hh, j*32 + k) + a0 * ldin<F32>(W_out, k);
    #pragma unroll
    for (int f = 0; f < 13; ++f) ws[4096 + j*16 + f] = wx[1 + f];
    #pragma unroll
    for (int f = 13; f < 16; ++f) ws[4096 + j*16 + f] = 0.0f;  // pad (never poison)
    float bo = ldin<F32>(b_out, 0);
    ws[6144 + j] = bg + a0 * bo;
    ws[6272 + j] = a0;
    ws[6400 + j] = bg;
    if (j < 32) ws[6528 + j] = ldin<F32>(W_out, j);
    if (j == 0) ws[6560] = bo;
}

// Weight-stationary LSTM: 1 wave per block, 16 sequences per wave.
// Lane owns unit u = lane&31, all 4 gate rows in VGPRs. No barriers.
template<bool F32>
__global__ __launch_bounds__(64, 2) void lstm_main(
    const void* __restrict__ pm25,   // (512, 8, 184, 1)
    const void* __restrict__ feat,   // (512, 32, 184, 13)
    const float* __restrict__ ws,
    void* __restrict__ out)          // (512, 24, 184, 1)
{
    __shared__ float hb[16][36];     // stride 36: 16B-aligned rows, 2-way bank alias only
    __shared__ float fb[16][16];     // staged features, this wave's 16 seqs
    if (ws[FLAG_OFF] != (F32 ? 1.0f : 0.0f)) return;

    const int lane = threadIdx.x;    // 0..63
    const int u    = lane & 31;
    const int half = lane >> 5;
    const int wseq = blockIdx.x * 16;

    // ---- load weights into registers (once) ----
    float4 Wh[4][8];                 // 128 VGPRs: Wh2 rows u, u+32, u+64, u+96
    float4 Wf3[4][3];                // 48 VGPRs: Wf cols 0..11
    float  Wf12[4], bg2r[4], a0r[4], bg0r[4];
    #pragma unroll
    for (int g = 0; g < 4; ++g) {
        const int row = u + 32*g;
        const float4* wr = (const float4*)(ws + row*32);
        #pragma unroll
        for (int q = 0; q < 8; ++q) Wh[g][q] = wr[q];
        const float4* wf = (const float4*)(ws + 4096 + row*16);
        #pragma unroll
        for (int q = 0; q < 3; ++q) Wf3[g][q] = wf[q];
        Wf12[g] = ws[4096 + row*16 + 12];
        bg2r[g] = ws[6144 + row];
        a0r[g]  = ws[6272 + row];
        bg0r[g] = ws[6400 + row];
    }
    const float wo = ws[6528 + u];
    const float bo = ws[6560];

    // ---- feature staging metadata: 208 floats / 64 lanes, 4 slots each ----
    long faddr[4]; int fsl[4], fff[4]; bool fok[4];
    #pragma unroll
    for (int j = 0; j < 4; ++j) {
        const int e = lane + 64*j;
        fok[j] = (e < 16*FEAT_);
        const int sl = e / FEAT_;
        const int f  = e - sl*FEAT_;
        fsl[j] = sl; fff[j] = f;
        const int seq  = wseq + (fok[j] ? sl : 0);
        const int b    = seq / CITY_;
        const int city = seq - b*CITY_;
        faddr[j] = ((long)(b*(HIST_+PRED_) + HIST_)*CITY_ + city)*FEAT_ + f;
    }

    float fval[4];
    auto ldfeat = [&]() {            // global -> regs (prefetch)
        #pragma unroll
        for (int j = 0; j < 4; ++j) {
            fval[j] = fok[j] ? ldin<F32>(feat, faddr[j]) : 0.0f;
            faddr[j] += CITY_ * FEAT_;
        }
    };
    auto wrfeat = [&]() {            // regs -> LDS
        #pragma unroll
        for (int j = 0; j < 4; ++j)
            if (fok[j]) fb[fsl[j]][fff[j]] = fval[j];
    };

    float cst[8];                    // c-state, one seq per round index

    auto round_body = [&](int t, int r, auto T0flag) {
        constexpr bool T0 = decltype(T0flag)::value;
        const int sl  = 2*r + half;
        const int seq = wseq + sl;
        float ai, af, ag, ao;
        if constexpr (T0) {
            const int b = seq / CITY_, city = seq - b*CITY_;
            const float x0 = ldin<F32>(pm25, (long)(b*HIST_ + (HIST_-1))*CITY_ + city);
            ai = fmaf(a0r[0], x0, bg0r[0]);
            af = 0.0f;
            ag = fmaf(a0r[2], x0, bg0r[2]);
            ao = fmaf(a0r[3], x0, bg0r[3]);
        } else {
            ai = bg2r[0]; af = bg2r[1]; ag = bg2r[2]; ao = bg2r[3];
            const float4* hp = (const float4*)(&hb[sl][0]);
            #pragma unroll
            for (int q = 0; q < 8; ++q) {
                const float4 h4 = hp[q];
                ai = fmaf(Wh[0][q].x, h4.x, ai); ai = fmaf(Wh[0][q].y, h4.y, ai);
                ai = fmaf(Wh[0][q].z, h4.z, ai); ai = fmaf(Wh[0][q].w, h4.w, ai);
                af = fmaf(Wh[1][q].x, h4.x, af); af = fmaf(Wh[1][q].y, h4.y, af);
                af = fmaf(Wh[1][q].z, h4.z, af); af = fmaf(Wh[1][q].w, h4.w, af);
                ag = fmaf(Wh[2][q].x, h4.x, ag); ag = fmaf(Wh[2][q].y, h4.y, ag);
                ag = fmaf(Wh[2][q].z, h4.z, ag); ag = fmaf(Wh[2][q].w, h4.w, ag);
                ao = fmaf(Wh[3][q].x, h4.x, ao); ao = fmaf(Wh[3][q].y, h4.y, ao);
                ao = fmaf(Wh[3][q].z, h4.z, ao); ao = fmaf(Wh[3][q].w, h4.w, ao);
            }
        }
        const float4* fp = (const float4*)(&fb[sl][0]);
        #pragma unroll
        for (int q = 0; q < 3; ++q) {
            const float4 f4 = fp[q];
            ai = fmaf(Wf3[0][q].x, f4.x, ai); ai = fmaf(Wf3[0][q].y, f4.y, ai);
            ai = fmaf(Wf3[0][q].z, f4.z, ai); ai = fmaf(Wf3[0][q].w, f4.w, ai);
            af = fmaf(Wf3[1][q].x, f4.x, af); af = fmaf(Wf3[1][q].y, f4.y, af);
            af = fmaf(Wf3[1][q].z, f4.z, af); af = fmaf(Wf3[1][q].w, f4.w, af);
            ag = fmaf(Wf3[2][q].x, f4.x, ag); ag = fmaf(Wf3[2][q].y, f4.y, ag);
            ag = fmaf(Wf3[2][q].z, f4.z, ag); ag = fmaf(Wf3[2][q].w, f4.w, ag);
            ao = fmaf(Wf3[3][q].x, f4.x, ao); ao = fmaf(Wf3[3][q].y, f4.y, ao);
            ao = fmaf(Wf3[3][q].z, f4.z, ao); ao = fmaf(Wf3[3][q].w, f4.w, ao);
        }
        const float f12 = fb[sl][12];
        ai = fmaf(Wf12[0], f12, ai);
        af = fmaf(Wf12[1], f12, af);
        ag = fmaf(Wf12[2], f12, ag);
        ao = fmaf(Wf12[3], f12, ao);

        const float I = sigf(ai), G = tanhf_(ag), O = sigf(ao);
        const float cc = T0 ? (I*G) : fmaf(sigf(af), cst[r], I*G);
        cst[r] = cc;
        const float hu = O * tanhf_(cc);
        hb[sl][u] = hu;

        float y = wo * hu;                     // y_t = wout . h_{t+1} + bout
        y += __shfl_xor(y, 1);
        y += __shfl_xor(y, 2);
        y += __shfl_xor(y, 4);
        y += __shfl_xor(y, 8);
        y += __shfl_xor(y, 16);
        if ((lane & 31) == 0) {
            const int b = seq / CITY_, city = seq - b*CITY_;
            stout<F32>(out, ((long)b*PRED_ + t)*CITY_ + city, y + bo);
        }
    };

    // ---- t = 0 ----
    ldfeat();            // t=0 features
    wrfeat();
    ldfeat();            // t=1 features in flight (hidden behind t=0 compute)
    #pragma unroll
    for (int r = 0; r < 8; ++r) round_body(0, r, TrueT{});

    // ---- t = 1..23 ----
    #pragma unroll 1
    for (int t = 1; t < PRED_; ++t) {
        wrfeat();                       // features for t (loaded last iter)
        if (t < PRED_-1) ldfeat();      // prefetch t+1 (guard: no OOB at t=23)
        #pragma unroll
        for (int r = 0; r < 8; ++r) round_body(t, r, FalseT{});
    }
}

extern "C" void kernel_launch(void* const* d_in, const int* in_sizes, int n_in,
                              void* d_out, int out_size, void* d_ws, size_t ws_size,
                              hipStream_t stream) {
    const void* pm25  = d_in[0];
    const void* feat  = d_in[1];
    const void* W_in  = d_in[2];
    const void* b_in  = d_in[3];
    const void* W_out = d_in[4];
    const void* b_out = d_in[5];
    const void* W_ih  = d_in[6];
    const void* W_hh  = d_in[7];
    const void* b_ih  = d_in[8];
    const void* b_hh  = d_in[9];
    float* ws = (float*)d_ws;

    detect_dtype<<<dim3(1), dim3(256), 0, stream>>>((const unsigned short*)feat, ws);

    lstm_prep<false><<<dim3(1), dim3(128), 0, stream>>>(
        W_in, b_in, W_out, b_out, W_ih, W_hh, b_ih, b_hh, ws);
    lstm_prep<true><<<dim3(1), dim3(128), 0, stream>>>(
        W_in, b_in, W_out, b_out, W_ih, W_hh, b_ih, b_hh, ws);

    lstm_main<false><<<dim3(BC_/16), dim3(64), 0, stream>>>(pm25, feat, ws, d_out);
    lstm_main<true ><<<dim3(BC_/16), dim3(64), 0, stream>>>(pm25, feat, ws, d_out);
}